// Round 2
// baseline (321.600 us; speedup 1.0000x reference)
//
#include <hip/hip_runtime.h>

// Depthwise transposed conv K=3, S=2, SAME. x:(8,128,128,128) NHWC fp32,
// w:(3,3,1,128) HWIO fp32 -> out:(8,256,256,128) fp32.
//
// Thread = (n, y, tg, c4): strip of TQ=4 input columns t = 4*tg .. 4*tg+3
// of input row y, producing 16 output float4s: out rows {2y, 2y+1} x cols
// {2t, 2t+1}. Sliding register window carries x[y,t-1], x[y-1,t-1]; all 9
// weight taps hoisted (amortized over 16 outputs).
//
// Lane map: lane&31 = c4 (contiguous 512B channel segment), lane bit 5 =
// adjacent column group -> every load/store covers two distinct fully
// populated 512B segments (complete 64B lines).
//
// ROUND-2 CHANGE (single variable): plain stores instead of
// __builtin_nontemporal_store. Evidence: kernel stuck at ~152-164us
// (~2.2 TB/s effective) across a 3x vmem-instruction reduction, while the
// m13 float4-copy (plain stores, same mixed read+write shape) does
// 6.29 TB/s. NT-store path is the invariant suspect; L2 "pollution" by the
// write stream is harmless (x is 64 MiB, L3-resident).
//
// out[2y+0, 2t+0] = w00*x[y,t] + w02*x[y,t-1] + w20*x[y-1,t] + w22*x[y-1,t-1]
// out[2y+0, 2t+1] = w01*x[y,t] + w21*x[y-1,t]
// out[2y+1, 2t+0] = w10*x[y,t] + w12*x[y,t-1]
// out[2y+1, 2t+1] = w11*x[y,t]

typedef float v4f __attribute__((ext_vector_type(4)));

__global__ __launch_bounds__(256) void upsample_tconv_kernel(
    const float* __restrict__ x, const float* __restrict__ w,
    float* __restrict__ out)
{
    // 8 * 128 * 32 * 32 = 1,048,576 threads
    int idx = blockIdx.x * blockDim.x + threadIdx.x;
    int c4 = idx & 31;            // float4 chunk of 128 channels
    int tg = (idx >> 5) & 31;     // input-column group of 4 (lane bit 5 = adjacent group)
    int y  = (idx >> 10) & 127;   // input row (wave-uniform)
    int n  = idx >> 17;           // batch

    // All 9 taps, loaded once per thread. w[j][i][c] -> (j*3+i)*32 + c4
    const v4f* wv = (const v4f*)w;
    v4f w00 = wv[0 * 32 + c4];
    v4f w01 = wv[1 * 32 + c4];
    v4f w02 = wv[2 * 32 + c4];
    v4f w10 = wv[3 * 32 + c4];
    v4f w11 = wv[4 * 32 + c4];
    v4f w12 = wv[5 * 32 + c4];
    v4f w20 = wv[6 * 32 + c4];
    v4f w21 = wv[7 * 32 + c4];
    v4f w22 = wv[8 * 32 + c4];

    const v4f zero = (v4f)(0.f);
    const v4f* xv = (const v4f*)x;   // ((n*128+y)*128+t)*32 + c4

    int t0 = tg << 2;
    int rowbase = ((n * 128 + y) * 128) * 32 + c4;   // x[y, 0]
    int upbase  = rowbase - 128 * 32;                // x[y-1, 0]
    bool has_up = (y > 0);                            // wave-uniform

    // Halo column t0-1 (zero at the left edge)
    v4f xpa = (t0 > 0) ? xv[rowbase + (t0 - 1) * 32] : zero;
    v4f xpc = (has_up && t0 > 0) ? xv[upbase + (t0 - 1) * 32] : zero;

    v4f* ov = (v4f*)out;
    int oy = y << 1;
    int ob0 = ((n * 256 + oy) * 256 + (t0 << 1)) * 32 + c4;  // out[2y,   2t0]
    int ob1 = ob0 + 256 * 32;                                // out[2y+1, 2t0]

    #pragma unroll
    for (int k = 0; k < 4; ++k) {
        v4f xa = xv[rowbase + (t0 + k) * 32];                 // x[y,   t]
        v4f xc = has_up ? xv[upbase + (t0 + k) * 32] : zero;  // x[y-1, t]

        v4f o_ee = w00 * xa + w02 * xpa + w20 * xc + w22 * xpc; // out[2y,  2t]
        v4f o_eo = w01 * xa + w21 * xc;                         // out[2y,  2t+1]
        v4f o_oe = w10 * xa + w12 * xpa;                        // out[2y+1,2t]
        v4f o_oo = w11 * xa;                                    // out[2y+1,2t+1]

        int o = ob0 + (k << 1) * 32;
        ov[o] = o_ee;
        ov[o + 32] = o_eo;
        o = ob1 + (k << 1) * 32;
        ov[o] = o_oe;
        ov[o + 32] = o_oo;

        xpa = xa;
        xpc = xc;
    }
}

extern "C" void kernel_launch(void* const* d_in, const int* in_sizes, int n_in,
                              void* d_out, int out_size, void* d_ws, size_t ws_size,
                              hipStream_t stream) {
    const float* x = (const float*)d_in[0];
    const float* w = (const float*)d_in[1];
    float* out = (float*)d_out;

    // 1,048,576 threads / 256 = 4096 blocks
    upsample_tconv_kernel<<<dim3(4096), dim3(256), 0, stream>>>(x, w, out);
}

// Round 3
// 312.841 us; speedup vs baseline: 1.0280x; 1.0280x over previous
//
#include <hip/hip_runtime.h>

// Depthwise transposed conv K=3, S=2, SAME. x:(8,128,128,128) NHWC fp32,
// w:(3,3,1,128) HWIO fp32 -> out:(8,256,256,128) fp32.
//
// ROUND-3 CHANGE: persistent streaming structure. Evidence: kernel stuck at
// ~152-164us (~2.2 TB/s) across 8x instruction reduction and NT/plain store
// swap -> not instruction- or store-path-bound. Per-wave lifetime arithmetic
// (64 waves/CU total, ~153us) shows waves stalled ~30us each: one-shot
// threads drain vmcnt to 0 once and die, so there is no sustained pipeline
// of outstanding loads (the m13 copy kernel that hits 6.29 TB/s is a
// persistent grid-stride loop). Fix: 1024 blocks (4/CU, fully resident),
// each thread sweeps 4 consecutive input rows of its 4-column strip with
// software-pipelined register rotation:
//   - prefetch row r+1's loads BEFORE computing/storing row r
//   - current row's registers become next row's "above" row (halves reads)
//
// Thread = (n, yb, tg, c4): input rows 4*yb..4*yb+3, input cols 4*tg..4*tg+3,
// channels 4*c4..4*c4+3. Produces 64 output float4s.
// Lane map: lane&31 = c4 (512B contiguous), lane bit5 = adjacent tg.
//
// out[2y+0, 2t+0] = w00*x[y,t] + w02*x[y,t-1] + w20*x[y-1,t] + w22*x[y-1,t-1]
// out[2y+0, 2t+1] = w01*x[y,t] + w21*x[y-1,t]
// out[2y+1, 2t+0] = w10*x[y,t] + w12*x[y,t-1]
// out[2y+1, 2t+1] = w11*x[y,t]

typedef float v4f __attribute__((ext_vector_type(4)));

__global__ __launch_bounds__(256) void upsample_tconv_kernel(
    const float* __restrict__ x, const float* __restrict__ w,
    float* __restrict__ out)
{
    // 8 * 32 * 32 * 32 = 262,144 threads = 1024 blocks (4 per CU)
    int idx = blockIdx.x * blockDim.x + threadIdx.x;
    int c4 = idx & 31;            // float4 chunk of 128 channels
    int tg = (idx >> 5) & 31;     // input-column group of 4 (lane bit5 = adjacent group)
    int yb = (idx >> 10) & 31;    // input-row group of 4
    int n  = idx >> 15;           // batch

    // All 9 taps. w[j][i][c] -> (j*3+i)*32 + c4
    const v4f* wv = (const v4f*)w;
    v4f w00 = wv[0 * 32 + c4];
    v4f w01 = wv[1 * 32 + c4];
    v4f w02 = wv[2 * 32 + c4];
    v4f w10 = wv[3 * 32 + c4];
    v4f w11 = wv[4 * 32 + c4];
    v4f w12 = wv[5 * 32 + c4];
    v4f w20 = wv[6 * 32 + c4];
    v4f w21 = wv[7 * 32 + c4];
    v4f w22 = wv[8 * 32 + c4];

    const v4f zero = (v4f)(0.f);
    const v4f* xv = (const v4f*)x;
    v4f* ov = (v4f*)out;

    int t0 = tg << 2;
    int y0 = yb << 2;
    bool lh = (t0 > 0);                              // left halo exists
    int rb = ((n * 128 + y0) * 128 + t0) * 32 + c4;  // x[y0, t0]; row stride 4096
    int ob = ((n * 256 + (y0 << 1)) * 256 + (t0 << 1)) * 32 + c4;  // out[2y0, 2t0]

    // Load one x row-chunk (halo col t0-1 + cols t0..t0+3) into 5 regs.
#define LOADROW(H, R0, R1, R2, R3, base) \
    do { int _b = (base); \
         H  = lh ? xv[_b - 32] : zero; \
         R0 = xv[_b];       R1 = xv[_b + 32]; \
         R2 = xv[_b + 64];  R3 = xv[_b + 96]; } while (0)

    // One input column t -> 4 output float4s (2 rows x 2 cols), NT stores.
#define KCOL(XA, XPA, XC, XPC, OO) \
    do { __builtin_nontemporal_store(w00*(XA) + w02*(XPA) + w20*(XC) + w22*(XPC), &ov[_o  + (OO)*32]); \
         __builtin_nontemporal_store(w01*(XA) + w21*(XC),                          &ov[_o  + ((OO)+1)*32]); \
         __builtin_nontemporal_store(w10*(XA) + w12*(XPA),                         &ov[_o2 + (OO)*32]); \
         __builtin_nontemporal_store(w11*(XA),                                     &ov[_o2 + ((OO)+1)*32]); } while (0)

    // One input row: A = x[y, *], C = x[y-1, *] -> out rows 2y, 2y+1.
#define ROW(AH, A0, A1, A2, A3, CH, C0, C1, C2, C3, OB) \
    do { int _o = (OB); int _o2 = _o + 8192; \
         KCOL(A0, AH, C0, CH, 0); \
         KCOL(A1, A0, C1, C0, 2); \
         KCOL(A2, A1, C2, C1, 4); \
         KCOL(A3, A2, C3, C2, 6); } while (0)

    // Prev row (y0-1): zeros at the top edge.
    v4f ch, c0, c1, c2, c3;
    if (y0 > 0) {
        LOADROW(ch, c0, c1, c2, c3, rb - 4096);
    } else {
        ch = zero; c0 = zero; c1 = zero; c2 = zero; c3 = zero;
    }
    // Current row y0.
    v4f ah, a0, a1, a2, a3;
    LOADROW(ah, a0, a1, a2, a3, rb);

    v4f nh, n0, n1, n2, n3;

    // r=0: prefetch row y0+1, compute row y0
    LOADROW(nh, n0, n1, n2, n3, rb + 4096);
    ROW(ah, a0, a1, a2, a3, ch, c0, c1, c2, c3, ob);
    // r=1: prefetch row y0+2 into C (dead), compute row y0+1 (cur=N, prev=A)
    LOADROW(ch, c0, c1, c2, c3, rb + 2 * 4096);
    ROW(nh, n0, n1, n2, n3, ah, a0, a1, a2, a3, ob + 2 * 8192);
    // r=2: prefetch row y0+3 into A (dead), compute row y0+2 (cur=C, prev=N)
    LOADROW(ah, a0, a1, a2, a3, rb + 3 * 4096);
    ROW(ch, c0, c1, c2, c3, nh, n0, n1, n2, n3, ob + 4 * 8192);
    // r=3: compute row y0+3 (cur=A, prev=C)
    ROW(ah, a0, a1, a2, a3, ch, c0, c1, c2, c3, ob + 6 * 8192);

#undef ROW
#undef KCOL
#undef LOADROW
}

extern "C" void kernel_launch(void* const* d_in, const int* in_sizes, int n_in,
                              void* d_out, int out_size, void* d_ws, size_t ws_size,
                              hipStream_t stream) {
    const float* x = (const float*)d_in[0];
    const float* w = (const float*)d_in[1];
    float* out = (float*)d_out;

    // 262,144 threads / 256 = 1024 blocks
    upsample_tconv_kernel<<<dim3(1024), dim3(256), 0, stream>>>(x, w, out);
}